// Round 6
// baseline (564.936 us; speedup 1.0000x reference)
//
#include <hip/hip_runtime.h>
#include <math.h>

#define N_SP 4096
#define DIMC 512
#define HEADS 8
#define HD 64
#define CH_STRIDE 1536   // per-batch channel stride of the qkv workspace region

typedef __attribute__((ext_vector_type(8))) short short8;
typedef __attribute__((ext_vector_type(4))) float f32x4;

__device__ __forceinline__ float elu1(float x) { return x > 0.f ? x + 1.f : expf(x); }

__device__ __forceinline__ float waveSum(float v) {
#pragma unroll
    for (int o = 1; o < 64; o <<= 1) v += __shfl_xor(v, o);
    return v;
}
__device__ __forceinline__ float waveMax(float v) {
#pragma unroll
    for (int o = 1; o < 64; o <<= 1) v = fmaxf(v, __shfl_xor(v, o));
    return v;
}

// fp32 -> bf16 with round-to-nearest-even, two packed into a uint
__device__ __forceinline__ unsigned short f2bf(float f) {
    union { float f; unsigned u; } v; v.f = f;
    unsigned r = v.u + 0x7fffu + ((v.u >> 16) & 1u);
    return (unsigned short)(r >> 16);
}
__device__ __forceinline__ unsigned pk2(float lo, float hi) {
    return (unsigned)f2bf(lo) | ((unsigned)f2bf(hi) << 16);
}

// async global->LDS, 16B per lane (wave-uniform LDS base + lane*16)
__device__ __forceinline__ void gload16(const unsigned short* g, unsigned short* l) {
    __builtin_amdgcn_global_load_lds(
        (const __attribute__((address_space(1))) unsigned int*)g,
        (__attribute__((address_space(3))) unsigned int*)l, 16, 0, 0);
}

// ---------------------------------------------------------------------------
// one-time fp32 -> bf16 convert (RNE, same rounding as old in-GEMM pk2)
// ---------------------------------------------------------------------------
__global__ __launch_bounds__(256) void convert_bf16(
    const float* __restrict__ src, unsigned short* __restrict__ dst, int n4)
{
    int i = blockIdx.x * 256 + threadIdx.x;
    if (i < n4) {
        float4 v = ((const float4*)src)[i];
        uint2 u; u.x = pk2(v.x, v.y); u.y = pk2(v.z, v.w);
        ((uint2*)dst)[i] = u;
    }
}

// ---------------------------------------------------------------------------
// x[b,c,n] fp32 -> xT[b,n,c] bf16 (K-contiguous operand for the GEMMs).
// ---------------------------------------------------------------------------
__global__ __launch_bounds__(256) void transpose_x(
    const float* __restrict__ X, unsigned short* __restrict__ XT)
{
    int ntile = blockIdx.x;   // 64 tiles of 64 n
    int ctile = blockIdx.y;   // 8 tiles of 64 c
    int b     = blockIdx.z;
    __shared__ float tile[64 * 65];
    int tid = threadIdx.x;
    int tr = tid >> 4;          // 0..15
    int tc = (tid & 15) * 4;    // 0..60
    const float* xb = X + ((size_t)b * DIMC + ctile * 64) * N_SP + ntile * 64;
#pragma unroll
    for (int i = 0; i < 4; i++) {
        int c = tr + i * 16;
        float4 v = *(const float4*)(xb + (size_t)c * N_SP + tc);
        float* d = &tile[c * 65 + tc];
        d[0] = v.x; d[1] = v.y; d[2] = v.z; d[3] = v.w;
    }
    __syncthreads();
    unsigned short* xt = XT + ((size_t)b * N_SP + ntile * 64) * DIMC + ctile * 64;
#pragma unroll
    for (int i = 0; i < 4; i++) {
        int n = tr + i * 16;
        uint2 u;
        u.x = pk2(tile[(tc + 0) * 65 + n], tile[(tc + 1) * 65 + n]);
        u.y = pk2(tile[(tc + 2) * 65 + n], tile[(tc + 3) * 65 + n]);
        *(uint2*)(xt + (size_t)n * DIMC + tc) = u;
    }
}

// ---------------------------------------------------------------------------
// gT[b,n,c] = bf16( res[b,512+c,n] * o[b,c,n] ), written into the dead
// v-channel region (ch 1024..1535) of the qkv workspace. Feeds proj GEMM.
// ---------------------------------------------------------------------------
__global__ __launch_bounds__(256) void gate_transpose(float* __restrict__ qkv)
{
    int ntile = blockIdx.x;
    int ctile = blockIdx.y;
    int b     = blockIdx.z;
    __shared__ float tile[64 * 65];
    int tid = threadIdx.x;
    int tr = tid >> 4;
    int tc = (tid & 15) * 4;
    const float* rb = qkv + ((size_t)b * CH_STRIDE + 512 + ctile * 64) * N_SP + ntile * 64;
    const float* ob = qkv + ((size_t)b * CH_STRIDE +       ctile * 64) * N_SP + ntile * 64;
#pragma unroll
    for (int i = 0; i < 4; i++) {
        int c = tr + i * 16;
        float4 r4 = *(const float4*)(rb + (size_t)c * N_SP + tc);
        float4 o4 = *(const float4*)(ob + (size_t)c * N_SP + tc);
        float* d = &tile[c * 65 + tc];
        d[0] = r4.x * o4.x; d[1] = r4.y * o4.y;
        d[2] = r4.z * o4.z; d[3] = r4.w * o4.w;
    }
    __syncthreads();
    unsigned short* gt = (unsigned short*)(qkv + ((size_t)b * CH_STRIDE + 1024) * N_SP)
                         + (size_t)(ntile * 64) * DIMC + ctile * 64;
#pragma unroll
    for (int i = 0; i < 4; i++) {
        int n = tr + i * 16;
        uint2 u;
        u.x = pk2(tile[(tc + 0) * 65 + n], tile[(tc + 1) * 65 + n]);
        u.y = pk2(tile[(tc + 2) * 65 + n], tile[(tc + 3) * 65 + n]);
        *(uint2*)(gt + (size_t)n * DIMC + tc) = u;
    }
}

// ---------------------------------------------------------------------------
// MFMA bf16 GEMM, m97 structure, single-buffer, BK=64:
// 8 K-steps (vs 16 at BK=32) -> half the barrier/vmcnt(0) drains, 32 MFMA
// per drain. Two K=32 slices computed sequentially reusing the same
// fragment registers (VGPR-flat). LDS 32 KB single-buffered.
// C[b, bo+m, n] = sum_c A[bo+m,c] * B[b, bn+n, c] + bias[bo+m]
// QKV_EPI: store elu1() for q/k channels (bo<1024) and accumulate
// qsum[b*512+ch] = sum_n elu1(q) via epilogue atomics (replaces qmean pass).
// ---------------------------------------------------------------------------
template<bool QKV_EPI>
__global__ __launch_bounds__(256) void gemm_bf16_fast(
    const unsigned short* __restrict__ A, const float* __restrict__ bias,
    const unsigned short* __restrict__ B, size_t bstride,
    float* __restrict__ C, int dst_cstride, float* __restrict__ qsum)
{
    __shared__ unsigned short Ws[8192];  // [8 kb][128 m][8]
    __shared__ unsigned short Xs[8192];  // [8 kb][128 n][8]
    int b  = blockIdx.z;
    int bo = blockIdx.y * 128;
    int bn = blockIdx.x * 128;
    const unsigned short* Ab = A + (size_t)bo * DIMC;
    const unsigned short* Bb = B + (size_t)b * bstride + (size_t)bn * DIMC;
    int tid  = threadIdx.x;
    int lane = tid & 63;
    int wid  = tid >> 6;
    int wm = (wid >> 1) * 64, wn = (wid & 1) * 64;
    int quad = lane >> 4, l16 = lane & 15;
    int r0  = tid & 127;    // staged row (wave-uniform base + lane)
    int kb0 = tid >> 7;     // 0 or 1; issues cover kb0, kb0+2, kb0+4, kb0+6

    f32x4 acc[4][4];
#pragma unroll
    for (int i = 0; i < 4; i++)
#pragma unroll
        for (int j = 0; j < 4; j++) acc[i][j] = f32x4{0.f, 0.f, 0.f, 0.f};

    for (int c0 = 0; c0 < DIMC; c0 += 64) {
        if (c0) __syncthreads();           // all waves done reading prev tile
#pragma unroll
        for (int g = 0; g < 4; g++) {
            int kb = kb0 + g * 2;
            gload16(Ab + (size_t)r0 * DIMC + c0 + kb * 8, &Ws[kb * 1024 + r0 * 8]);
            gload16(Bb + (size_t)r0 * DIMC + c0 + kb * 8, &Xs[kb * 1024 + r0 * 8]);
        }
        __syncthreads();                   // vmcnt(0) drain -> tile resident
#pragma unroll
        for (int s = 0; s < 2; s++) {      // two K=32 slices, regs reused
            short8 af[4], bfr[4];
            int cb = (quad + s * 4) * 1024;
#pragma unroll
            for (int i = 0; i < 4; i++) {
                af[i]  = *(const short8*)&Ws[cb + (wm + i * 16 + l16) * 8];
                bfr[i] = *(const short8*)&Xs[cb + (wn + i * 16 + l16) * 8];
            }
#pragma unroll
            for (int i = 0; i < 4; i++)
#pragma unroll
                for (int j = 0; j < 4; j++)
                    acc[i][j] = __builtin_amdgcn_mfma_f32_16x16x32_bf16(
                        af[i], bfr[j], acc[i][j], 0, 0, 0);
        }
    }
    float* Cb = C + (size_t)b * dst_cstride * N_SP;
    bool is_q   = QKV_EPI && (bo < 512);
    bool do_elu = QKV_EPI && (bo < 1024);
#pragma unroll
    for (int i = 0; i < 4; i++) {
        int row0 = bo + wm + i * 16 + quad * 4;
#pragma unroll
        for (int r = 0; r < 4; r++) {
            float bi = bias[row0 + r];
            float vj[4];
#pragma unroll
            for (int j = 0; j < 4; j++) {
                float v = acc[i][j][r] + bi;
                if (do_elu) v = elu1(v);
                vj[j] = v;
            }
            float* cr = Cb + (size_t)(row0 + r) * N_SP + bn + wn + l16;
#pragma unroll
            for (int j = 0; j < 4; j++) cr[j * 16] = vj[j];
            if (is_q) {
                float s = vj[0] + vj[1] + vj[2] + vj[3];
                s += __shfl_xor(s, 1); s += __shfl_xor(s, 2);
                s += __shfl_xor(s, 4); s += __shfl_xor(s, 8);
                if (l16 == 0)
                    atomicAdd(&qsum[(size_t)b * 512 + row0 + r], s);
            }
        }
    }
}

// ---------------------------------------------------------------------------
// logits[bh,t] = (0.125/N) * sum_d qsum[d]*k'[d,t]   (k' already elu1'd)
// ---------------------------------------------------------------------------
__global__ __launch_bounds__(256) void logits_kernel(
    const float* __restrict__ QKV, const float* __restrict__ qsum,
    float* __restrict__ eff)
{
    int tc = blockIdx.x, h = blockIdx.y, b = blockIdx.z;
    int tid = threadIdx.x;
    int t = tc * 256 + tid;
    __shared__ float qm[64];
    if (tid < 64)
        qm[tid] = qsum[(size_t)b * 512 + h * 64 + tid] * (0.125f / (float)N_SP);
    __syncthreads();
    const float* kb = QKV + ((size_t)b * CH_STRIDE + 512 + h * 64) * N_SP;
    float s = 0.f;
#pragma unroll 8
    for (int d = 0; d < 64; d++) s += qm[d] * kb[(size_t)d * N_SP + t];
    eff[((size_t)b * 8 + h) * N_SP + t] = s;
}

// ---------------------------------------------------------------------------
// in-place softmax over t per (b,h); stores p[t] = N * softmax(logits)[t]
// ---------------------------------------------------------------------------
__global__ __launch_bounds__(256) void softmax_kernel(float* __restrict__ eff)
{
    int bh = blockIdx.x;
    float* row = eff + (size_t)bh * N_SP;
    int tid = threadIdx.x;
    float4 v[4];
#pragma unroll
    for (int j = 0; j < 4; j++) v[j] = ((float4*)row)[j * 256 + tid];
    float m = -1e30f;
#pragma unroll
    for (int j = 0; j < 4; j++)
        m = fmaxf(m, fmaxf(fmaxf(v[j].x, v[j].y), fmaxf(v[j].z, v[j].w)));
    m = waveMax(m);
    __shared__ float red[8];
    if ((tid & 63) == 0) red[tid >> 6] = m;
    __syncthreads();
    m = fmaxf(fmaxf(red[0], red[1]), fmaxf(red[2], red[3]));
    float s = 0.f;
#pragma unroll
    for (int j = 0; j < 4; j++) {
        v[j].x = expf(v[j].x - m); v[j].y = expf(v[j].y - m);
        v[j].z = expf(v[j].z - m); v[j].w = expf(v[j].w - m);
        s += v[j].x + v[j].y + v[j].z + v[j].w;
    }
    float ws = waveSum(s);
    if ((tid & 63) == 0) red[4 + (tid >> 6)] = ws;
    __syncthreads();
    float tot = red[4] + red[5] + red[6] + red[7];
    float sc = (float)N_SP / tot;
#pragma unroll
    for (int j = 0; j < 4; j++) {
        v[j].x *= sc; v[j].y *= sc; v[j].z *= sc; v[j].w *= sc;
        ((float4*)row)[j * 256 + tid] = v[j];
    }
}

// ---------------------------------------------------------------------------
// kv[bh,d,e] = (1/N) sum_t rope(k'*p)[t,d] * v[t,e]     (k' already elu1'd)
// kmean[bh,d] = (1/N) sum_t (k'*p)[t,d]
// ---------------------------------------------------------------------------
__global__ __launch_bounds__(256) void kv_kernel(
    const float* __restrict__ QKV, const float* __restrict__ eff,
    const float* __restrict__ sinp, const float* __restrict__ cosp,
    float* __restrict__ kv, float* __restrict__ kmean)
{
    int sp = blockIdx.x;
    int h = blockIdx.y, b = blockIdx.z;
    int bh = b * 8 + h;
    int tid = threadIdx.x;
    int r = tid >> 2, quad = tid & 3;
    const float* krow = QKV + ((size_t)b * CH_STRIDE + 512 + h * 64 + r) * N_SP;
    const float* vrow = QKV + ((size_t)b * CH_STRIDE + 1024 + h * 64 + r) * N_SP;
    const float* prow = eff + (size_t)bh * N_SP;
    __shared__ float ksr[64 * 65];
    __shared__ float vs[64 * 65];
    int dg = tid >> 4, eg = tid & 15;
    float acc[4][4];
#pragma unroll
    for (int i = 0; i < 4; i++)
#pragma unroll
        for (int j = 0; j < 4; j++) acc[i][j] = 0.f;
    float km = 0.f;
    float sgn = (r & 1) ? 1.f : -1.f;

    for (int c = 0; c < 8; c++) {
        int t0 = sp * 512 + c * 64;
        int tb = t0 + quad * 16;
        float kx[16], vv[16];
#pragma unroll
        for (int i4 = 0; i4 < 4; i4++) {
            float4 kf = *(const float4*)(krow + tb + i4 * 4);
            float4 pf = *(const float4*)(prow + tb + i4 * 4);
            float4 vf = *(const float4*)(vrow + tb + i4 * 4);
            kx[i4 * 4 + 0] = kf.x * pf.x;
            kx[i4 * 4 + 1] = kf.y * pf.y;
            kx[i4 * 4 + 2] = kf.z * pf.z;
            kx[i4 * 4 + 3] = kf.w * pf.w;
            vv[i4 * 4 + 0] = vf.x; vv[i4 * 4 + 1] = vf.y;
            vv[i4 * 4 + 2] = vf.z; vv[i4 * 4 + 3] = vf.w;
        }
#pragma unroll
        for (int i = 0; i < 16; i++) km += kx[i];
        __syncthreads();
#pragma unroll
        for (int i = 0; i < 16; i++) {
            float partner = __shfl_xor(kx[i], 4);
            int t = tb + i;
            float sv = sinp[(size_t)t * 64 + r];
            float cv = cosp[(size_t)t * 64 + r];
            float kr = kx[i] * cv + sgn * partner * sv;
            ksr[r * 65 + (t - t0)] = kr;
            vs[r * 65 + (t - t0)] = vv[i];
        }
        __syncthreads();
#pragma unroll 8
        for (int t = 0; t < 64; t++) {
            float a[4], bb[4];
#pragma unroll
            for (int i = 0; i < 4; i++) a[i] = ksr[(dg * 4 + i) * 65 + t];
#pragma unroll
            for (int j = 0; j < 4; j++) bb[j] = vs[(eg * 4 + j) * 65 + t];
#pragma unroll
            for (int i = 0; i < 4; i++)
#pragma unroll
                for (int j = 0; j < 4; j++) acc[i][j] += a[i] * bb[j];
        }
    }
#pragma unroll
    for (int i = 0; i < 4; i++)
#pragma unroll
        for (int j = 0; j < 4; j++)
            atomicAdd(&kv[((size_t)bh * 64 + dg * 4 + i) * 64 + eg * 4 + j],
                      acc[i][j] * (1.f / N_SP));
    km += __shfl_xor(km, 1);
    km += __shfl_xor(km, 2);
    if (quad == 0) atomicAdd(&kmean[(size_t)bh * 64 + r], km * (1.f / N_SP));
}

// ---------------------------------------------------------------------------
// res[b, 512 + h*64+e, t] = z[t] * sum_d qrope[t,d]*kv[d,e]   (q' already elu1'd)
// ---------------------------------------------------------------------------
__global__ __launch_bounds__(256) void res_kernel(
    const float* __restrict__ QKV, const float* __restrict__ kv,
    const float* __restrict__ kmean,
    const float* __restrict__ sinp, const float* __restrict__ cosp,
    float* __restrict__ res)
{
    int tc = blockIdx.x;
    int h = blockIdx.y, b = blockIdx.z;
    int bh = b * 8 + h;
    int tid = threadIdx.x;
    int t0 = tc * 64;
    __shared__ float qsr[64 * 65];
    __shared__ float qse[64 * 65];
    __shared__ float kvs[64 * 65];
    __shared__ float zs[64];
    __shared__ float kms[64];
#pragma unroll
    for (int j = 0; j < 16; j++) {
        int lin = j * 256 + tid;
        kvs[(lin >> 6) * 65 + (lin & 63)] = kv[(size_t)bh * 4096 + lin];
    }
    if (tid < 64) kms[tid] = kmean[(size_t)bh * 64 + tid];

    int r = tid >> 2, quad = tid & 3;
    const float* qrow = QKV + ((size_t)b * CH_STRIDE + h * 64 + r) * N_SP;
    float sgn = (r & 1) ? 1.f : -1.f;
    int tb = t0 + quad * 16;
#pragma unroll
    for (int i4 = 0; i4 < 4; i4++) {
        float4 qf = *(const float4*)(qrow + tb + i4 * 4);
        float qe[4] = { qf.x, qf.y, qf.z, qf.w };
#pragma unroll
        for (int ii = 0; ii < 4; ii++) {
            float partner = __shfl_xor(qe[ii], 4);
            int t = tb + i4 * 4 + ii;
            float sv = sinp[(size_t)t * 64 + r];
            float cv = cosp[(size_t)t * 64 + r];
            qse[r * 65 + (t - t0)] = qe[ii];
            qsr[r * 65 + (t - t0)] = qe[ii] * cv + sgn * partner * sv;
        }
    }
    __syncthreads();
    if (tid < 64) {
        float s = 0.f;
#pragma unroll 8
        for (int d = 0; d < 64; d++) s += qse[d * 65 + tid] * kms[d];
        zs[tid] = 1.f / (s + 1e-6f);
    }
    __syncthreads();

    int eg = tid >> 4, tg = tid & 15;
    float acc[4][4];
#pragma unroll
    for (int j = 0; j < 4; j++)
#pragma unroll
        for (int i = 0; i < 4; i++) acc[j][i] = 0.f;
#pragma unroll 4
    for (int d = 0; d < 64; d++) {
        float qv[4], kvv[4];
#pragma unroll
        for (int i = 0; i < 4; i++) qv[i] = qsr[d * 65 + tg * 4 + i];
#pragma unroll
        for (int j = 0; j < 4; j++) kvv[j] = kvs[d * 65 + eg * 4 + j];
#pragma unroll
        for (int j = 0; j < 4; j++)
#pragma unroll
            for (int i = 0; i < 4; i++) acc[j][i] += kvv[j] * qv[i];
    }
    float* rb = res + ((size_t)b * CH_STRIDE + 512 + h * 64) * N_SP;
#pragma unroll
    for (int j = 0; j < 4; j++) {
        float4 o4;
        o4.x = acc[j][0] * zs[tg * 4 + 0];
        o4.y = acc[j][1] * zs[tg * 4 + 1];
        o4.z = acc[j][2] * zs[tg * 4 + 2];
        o4.w = acc[j][3] * zs[tg * 4 + 3];
        *(float4*)(rb + (size_t)(eg * 4 + j) * N_SP + t0 + tg * 4) = o4;
    }
}

// ---------------------------------------------------------------------------
// lepe: res[b, 512+c, n] += b_lepe[c] + depthwise 5x5 conv of v channel c.
// ---------------------------------------------------------------------------
#define LPS 73   // padded LDS row stride (floats)
__global__ __launch_bounds__(256) void lepe_kernel(
    const float* __restrict__ QKV, const float* __restrict__ wl,
    const float* __restrict__ bl, float* __restrict__ res)
{
    int c = blockIdx.x & 511;
    int b = blockIdx.x >> 9;
    __shared__ float img[68 * LPS];
    int tid = threadIdx.x;
    const float* vb = QKV + ((size_t)b * CH_STRIDE + 1024 + c) * N_SP;

    for (int i = tid; i < 68 * LPS; i += 256) img[i] = 0.f;
    __syncthreads();
#pragma unroll
    for (int i = 0; i < 4; i++) {
        int p = i * 256 + tid;          // float4 index
        float4 v4 = ((const float4*)vb)[p];
        int y = p >> 4;
        int x = (p & 15) * 4;
        float* dst = &img[(y + 2) * LPS + (x + 2)];
        dst[0] = v4.x; dst[1] = v4.y; dst[2] = v4.z; dst[3] = v4.w;
    }
    float w[25];
    const float* wc = wl + c * 25;
#pragma unroll
    for (int i = 0; i < 25; i++) w[i] = wc[i];
    float bias = bl[c];
    __syncthreads();

    int y  = tid >> 2;
    int x0 = (tid & 3) * 16;
    float acc[16];
#pragma unroll
    for (int u = 0; u < 16; u++) acc[u] = bias;
#pragma unroll
    for (int i = 0; i < 5; i++) {
        float rowv[20];
#pragma unroll
        for (int q = 0; q < 20; q++)
            rowv[q] = img[(y + i) * LPS + x0 + q];
#pragma unroll
        for (int j = 0; j < 5; j++)
#pragma unroll
            for (int u = 0; u < 16; u++)
                acc[u] += rowv[u + j] * w[i * 5 + j];
    }
    float* rr = res + ((size_t)b * CH_STRIDE + 512 + c) * N_SP + y * 64 + x0;
#pragma unroll
    for (int q = 0; q < 4; q++) {
        float4 r4 = *(const float4*)&rr[q * 4];
        r4.x += acc[q * 4 + 0]; r4.y += acc[q * 4 + 1];
        r4.z += acc[q * 4 + 2]; r4.w += acc[q * 4 + 3];
        *(float4*)&rr[q * 4] = r4;
    }
}

// ---------------------------------------------------------------------------
extern "C" void kernel_launch(void* const* d_in, const int* in_sizes, int n_in,
                              void* d_out, int out_size, void* d_ws, size_t ws_size,
                              hipStream_t stream)
{
    const float* x      = (const float*)d_in[0];
    const float* sinp   = (const float*)d_in[1];
    const float* cosp   = (const float*)d_in[2];
    const float* w_qkvo = (const float*)d_in[3];
    const float* b_qkvo = (const float*)d_in[4];
    const float* w_lepe = (const float*)d_in[5];
    const float* b_lepe = (const float*)d_in[6];
    const float* w_proj = (const float*)d_in[7];
    const float* b_proj = (const float*)d_in[8];
    float* out = (float*)d_out;
    float* ws  = (float*)d_ws;

    // workspace layout (float offsets) — unchanged ~203.5 MB layout:
    float* qkv   = ws;                        // 8*1536*4096 = 50331648
    float* eff   = ws + 50331648;             // 64*4096     = 262144
    float* qmean = ws + 50593792;             // 64*64       = 4096  (raw sums now)
    float* kmean = ws + 50597888;             // 64*64       = 4096
    float* kv    = ws + 50601984;             // 64*64*64    = 262144

    // scratch overlays (no workspace growth):
    unsigned short* xT    = (unsigned short*)out;                     // 8*4096*512
    unsigned short* wq_bf = (unsigned short*)out + 16777216;          // 2048*512
    unsigned short* wp_bf = (unsigned short*)kv;                      // 512*512
    unsigned short* gT    = (unsigned short*)(qkv + (size_t)1024 * N_SP);

    // zero qsum + kmean + kv (contiguous)
    hipMemsetAsync(qmean, 0, (4096 + 4096 + 262144) * sizeof(float), stream);

    convert_bf16<<<1024, 256, 0, stream>>>(w_qkvo, wq_bf, 262144);
    transpose_x<<<dim3(64, 8, 8), 256, 0, stream>>>(x, xT);

    // QKV GEMM: stores elu1(q), elu1(k), raw v; accumulates qsum atomics
    gemm_bf16_fast<true><<<dim3(32, 12, 8), 256, 0, stream>>>(
        wq_bf, b_qkvo, xT, (size_t)N_SP * DIMC, qkv, CH_STRIDE, qmean);

    logits_kernel<<<dim3(16, 8, 8), 256, 0, stream>>>(qkv, qmean, eff);
    softmax_kernel<<<64, 256, 0, stream>>>(eff);
    kv_kernel<<<dim3(8, 8, 8), 256, 0, stream>>>(qkv, eff, sinp, cosp, kv, kmean);
    res_kernel<<<dim3(64, 8, 8), 256, 0, stream>>>(qkv, kv, kmean, sinp, cosp, qkv);

    convert_bf16<<<256, 256, 0, stream>>>(w_proj, wp_bf, 65536);  // kv region dead now
    lepe_kernel<<<4096, 256, 0, stream>>>(qkv, w_lepe, b_lepe, qkv);

    // o = W_o x  -> overwrite dead q region (ch 0..511)
    gemm_bf16_fast<false><<<dim3(32, 4, 8), 256, 0, stream>>>(
        wq_bf + (size_t)1536 * DIMC, b_qkvo + 1536, xT, (size_t)N_SP * DIMC,
        qkv, CH_STRIDE, nullptr);

    // gT = bf16((res+lepe) * o), transposed into dead v region
    gate_transpose<<<dim3(64, 8, 8), 256, 0, stream>>>(qkv);

    // out = W_proj gT + b_proj
    gemm_bf16_fast<false><<<dim3(32, 4, 8), 256, 0, stream>>>(
        wp_bf, b_proj, gT, (size_t)CH_STRIDE * N_SP * 2, out, DIMC, nullptr);
}

// Round 7
// 554.840 us; speedup vs baseline: 1.0182x; 1.0182x over previous
//
#include <hip/hip_runtime.h>
#include <math.h>

#define N_SP 4096
#define DIMC 512
#define HEADS 8
#define HD 64
#define CH_STRIDE 1536   // per-batch channel stride of the qkv workspace region

typedef __attribute__((ext_vector_type(8))) short short8;
typedef __attribute__((ext_vector_type(4))) float f32x4;

// fast exp via hardware v_exp_f32 (2^x); ~1 ulp vs libm expf
__device__ __forceinline__ float fexp(float x) {
    return __builtin_amdgcn_exp2f(x * 1.4426950408889634f);
}
__device__ __forceinline__ float elu1(float x) { return x > 0.f ? x + 1.f : fexp(x); }

__device__ __forceinline__ float waveSum(float v) {
#pragma unroll
    for (int o = 1; o < 64; o <<= 1) v += __shfl_xor(v, o);
    return v;
}
__device__ __forceinline__ float waveMax(float v) {
#pragma unroll
    for (int o = 1; o < 64; o <<= 1) v = fmaxf(v, __shfl_xor(v, o));
    return v;
}

// fp32 -> bf16 with round-to-nearest-even, two packed into a uint
__device__ __forceinline__ unsigned short f2bf(float f) {
    union { float f; unsigned u; } v; v.f = f;
    unsigned r = v.u + 0x7fffu + ((v.u >> 16) & 1u);
    return (unsigned short)(r >> 16);
}
__device__ __forceinline__ unsigned pk2(float lo, float hi) {
    return (unsigned)f2bf(lo) | ((unsigned)f2bf(hi) << 16);
}

// async global->LDS, 16B per lane (wave-uniform LDS base + lane*16)
__device__ __forceinline__ void gload16(const unsigned short* g, unsigned short* l) {
    __builtin_amdgcn_global_load_lds(
        (const __attribute__((address_space(1))) unsigned int*)g,
        (__attribute__((address_space(3))) unsigned int*)l, 16, 0, 0);
}

// ---------------------------------------------------------------------------
// one-time fp32 -> bf16 convert (RNE, same rounding as old in-GEMM pk2)
// ---------------------------------------------------------------------------
__global__ __launch_bounds__(256) void convert_bf16(
    const float* __restrict__ src, unsigned short* __restrict__ dst, int n4)
{
    int i = blockIdx.x * 256 + threadIdx.x;
    if (i < n4) {
        float4 v = ((const float4*)src)[i];
        uint2 u; u.x = pk2(v.x, v.y); u.y = pk2(v.z, v.w);
        ((uint2*)dst)[i] = u;
    }
}

// ---------------------------------------------------------------------------
// x[b,c,n] fp32 -> xT[b,n,c] bf16 (K-contiguous operand for the GEMMs).
// ---------------------------------------------------------------------------
__global__ __launch_bounds__(256) void transpose_x(
    const float* __restrict__ X, unsigned short* __restrict__ XT)
{
    int ntile = blockIdx.x;   // 64 tiles of 64 n
    int ctile = blockIdx.y;   // 8 tiles of 64 c
    int b     = blockIdx.z;
    __shared__ float tile[64 * 65];
    int tid = threadIdx.x;
    int tr = tid >> 4;          // 0..15
    int tc = (tid & 15) * 4;    // 0..60
    const float* xb = X + ((size_t)b * DIMC + ctile * 64) * N_SP + ntile * 64;
#pragma unroll
    for (int i = 0; i < 4; i++) {
        int c = tr + i * 16;
        float4 v = *(const float4*)(xb + (size_t)c * N_SP + tc);
        float* d = &tile[c * 65 + tc];
        d[0] = v.x; d[1] = v.y; d[2] = v.z; d[3] = v.w;
    }
    __syncthreads();
    unsigned short* xt = XT + ((size_t)b * N_SP + ntile * 64) * DIMC + ctile * 64;
#pragma unroll
    for (int i = 0; i < 4; i++) {
        int n = tr + i * 16;
        uint2 u;
        u.x = pk2(tile[(tc + 0) * 65 + n], tile[(tc + 1) * 65 + n]);
        u.y = pk2(tile[(tc + 2) * 65 + n], tile[(tc + 3) * 65 + n]);
        *(uint2*)(xt + (size_t)n * DIMC + tc) = u;
    }
}

// ---------------------------------------------------------------------------
// gT[b,n,c] = bf16( res[b,512+c,n] * o[b,c,n] ), written into the dead
// v-channel region (ch 1024..1535) of the qkv workspace. Feeds proj GEMM.
// ---------------------------------------------------------------------------
__global__ __launch_bounds__(256) void gate_transpose(float* __restrict__ qkv)
{
    int ntile = blockIdx.x;
    int ctile = blockIdx.y;
    int b     = blockIdx.z;
    __shared__ float tile[64 * 65];
    int tid = threadIdx.x;
    int tr = tid >> 4;
    int tc = (tid & 15) * 4;
    const float* rb = qkv + ((size_t)b * CH_STRIDE + 512 + ctile * 64) * N_SP + ntile * 64;
    const float* ob = qkv + ((size_t)b * CH_STRIDE +       ctile * 64) * N_SP + ntile * 64;
#pragma unroll
    for (int i = 0; i < 4; i++) {
        int c = tr + i * 16;
        float4 r4 = *(const float4*)(rb + (size_t)c * N_SP + tc);
        float4 o4 = *(const float4*)(ob + (size_t)c * N_SP + tc);
        float* d = &tile[c * 65 + tc];
        d[0] = r4.x * o4.x; d[1] = r4.y * o4.y;
        d[2] = r4.z * o4.z; d[3] = r4.w * o4.w;
    }
    __syncthreads();
    unsigned short* gt = (unsigned short*)(qkv + ((size_t)b * CH_STRIDE + 1024) * N_SP)
                         + (size_t)(ntile * 64) * DIMC + ctile * 64;
#pragma unroll
    for (int i = 0; i < 4; i++) {
        int n = tr + i * 16;
        uint2 u;
        u.x = pk2(tile[(tc + 0) * 65 + n], tile[(tc + 1) * 65 + n]);
        u.y = pk2(tile[(tc + 2) * 65 + n], tile[(tc + 3) * 65 + n]);
        *(uint2*)(gt + (size_t)n * DIMC + tc) = u;
    }
}

// ---------------------------------------------------------------------------
// MFMA bf16 GEMM, m97 structure (single-buffer BK=32 K-loop — best measured).
// C[b, bo+m, n] = sum_c A[bo+m,c] * B[b, bn+n, c] + bias[bo+m]
// QKV_EPI: store elu1() for q/k channels (bo<1024) and accumulate
// qsum[b*512+ch] = sum_n elu1(q) via epilogue atomics (replaces qmean pass).
// elu1 uses hardware exp2 (v_exp_f32) — ~3 VALU ops vs ~20 for libm expf.
// ---------------------------------------------------------------------------
template<bool QKV_EPI>
__global__ __launch_bounds__(256) void gemm_bf16_fast(
    const unsigned short* __restrict__ A, const float* __restrict__ bias,
    const unsigned short* __restrict__ B, size_t bstride,
    float* __restrict__ C, int dst_cstride, float* __restrict__ qsum)
{
    __shared__ unsigned short Ws[4096];  // [4 kb][128 m][8]
    __shared__ unsigned short Xs[4096];  // [4 kb][128 n][8]
    int b  = blockIdx.z;
    int bo = blockIdx.y * 128;
    int bn = blockIdx.x * 128;
    const unsigned short* Ab = A + (size_t)bo * DIMC;
    const unsigned short* Bb = B + (size_t)b * bstride + (size_t)bn * DIMC;
    int tid  = threadIdx.x;
    int lane = tid & 63;
    int wid  = tid >> 6;
    int wm = (wid >> 1) * 64, wn = (wid & 1) * 64;
    int quad = lane >> 4, l16 = lane & 15;
    int r0  = tid & 127;    // staged row (wave-uniform base + lane)
    int kb0 = tid >> 7;     // 0 or 1; second issue covers kb0+2

    f32x4 acc[4][4];
#pragma unroll
    for (int i = 0; i < 4; i++)
#pragma unroll
        for (int j = 0; j < 4; j++) acc[i][j] = f32x4{0.f, 0.f, 0.f, 0.f};

    for (int c0 = 0; c0 < DIMC; c0 += 32) {
        if (c0) __syncthreads();
        gload16(Ab + (size_t)r0 * DIMC + c0 + kb0 * 8,       &Ws[kb0 * 1024 + r0 * 8]);
        gload16(Ab + (size_t)r0 * DIMC + c0 + (kb0 + 2) * 8, &Ws[(kb0 + 2) * 1024 + r0 * 8]);
        gload16(Bb + (size_t)r0 * DIMC + c0 + kb0 * 8,       &Xs[kb0 * 1024 + r0 * 8]);
        gload16(Bb + (size_t)r0 * DIMC + c0 + (kb0 + 2) * 8, &Xs[(kb0 + 2) * 1024 + r0 * 8]);
        __syncthreads();
        short8 af[4], bf[4];
#pragma unroll
        for (int i = 0; i < 4; i++) {
            af[i] = *(const short8*)&Ws[quad * 1024 + (wm + i * 16 + l16) * 8];
            bf[i] = *(const short8*)&Xs[quad * 1024 + (wn + i * 16 + l16) * 8];
        }
#pragma unroll
        for (int i = 0; i < 4; i++)
#pragma unroll
            for (int j = 0; j < 4; j++)
                acc[i][j] = __builtin_amdgcn_mfma_f32_16x16x32_bf16(
                    af[i], bf[j], acc[i][j], 0, 0, 0);
    }
    float* Cb = C + (size_t)b * dst_cstride * N_SP;
    bool is_q   = QKV_EPI && (bo < 512);
    bool do_elu = QKV_EPI && (bo < 1024);
#pragma unroll
    for (int i = 0; i < 4; i++) {
        int row0 = bo + wm + i * 16 + quad * 4;
#pragma unroll
        for (int r = 0; r < 4; r++) {
            float bi = bias[row0 + r];
            float vj[4];
#pragma unroll
            for (int j = 0; j < 4; j++) {
                float v = acc[i][j][r] + bi;
                if (do_elu) v = elu1(v);
                vj[j] = v;
            }
            float* cr = Cb + (size_t)(row0 + r) * N_SP + bn + wn + l16;
#pragma unroll
            for (int j = 0; j < 4; j++) cr[j * 16] = vj[j];
            if (is_q) {
                float s = vj[0] + vj[1] + vj[2] + vj[3];
                s += __shfl_xor(s, 1); s += __shfl_xor(s, 2);
                s += __shfl_xor(s, 4); s += __shfl_xor(s, 8);
                if (l16 == 0)
                    atomicAdd(&qsum[(size_t)b * 512 + row0 + r], s);
            }
        }
    }
}

// ---------------------------------------------------------------------------
// logits[bh,t] = (0.125/N) * sum_d qsum[d]*k'[d,t]   (k' already elu1'd)
// ---------------------------------------------------------------------------
__global__ __launch_bounds__(256) void logits_kernel(
    const float* __restrict__ QKV, const float* __restrict__ qsum,
    float* __restrict__ eff)
{
    int tc = blockIdx.x, h = blockIdx.y, b = blockIdx.z;
    int tid = threadIdx.x;
    int t = tc * 256 + tid;
    __shared__ float qm[64];
    if (tid < 64)
        qm[tid] = qsum[(size_t)b * 512 + h * 64 + tid] * (0.125f / (float)N_SP);
    __syncthreads();
    const float* kb = QKV + ((size_t)b * CH_STRIDE + 512 + h * 64) * N_SP;
    float s = 0.f;
#pragma unroll 8
    for (int d = 0; d < 64; d++) s += qm[d] * kb[(size_t)d * N_SP + t];
    eff[((size_t)b * 8 + h) * N_SP + t] = s;
}

// ---------------------------------------------------------------------------
// in-place softmax over t per (b,h); stores p[t] = N * softmax(logits)[t]
// ---------------------------------------------------------------------------
__global__ __launch_bounds__(256) void softmax_kernel(float* __restrict__ eff)
{
    int bh = blockIdx.x;
    float* row = eff + (size_t)bh * N_SP;
    int tid = threadIdx.x;
    float4 v[4];
#pragma unroll
    for (int j = 0; j < 4; j++) v[j] = ((float4*)row)[j * 256 + tid];
    float m = -1e30f;
#pragma unroll
    for (int j = 0; j < 4; j++)
        m = fmaxf(m, fmaxf(fmaxf(v[j].x, v[j].y), fmaxf(v[j].z, v[j].w)));
    m = waveMax(m);
    __shared__ float red[8];
    if ((tid & 63) == 0) red[tid >> 6] = m;
    __syncthreads();
    m = fmaxf(fmaxf(red[0], red[1]), fmaxf(red[2], red[3]));
    float s = 0.f;
#pragma unroll
    for (int j = 0; j < 4; j++) {
        v[j].x = fexp(v[j].x - m); v[j].y = fexp(v[j].y - m);
        v[j].z = fexp(v[j].z - m); v[j].w = fexp(v[j].w - m);
        s += v[j].x + v[j].y + v[j].z + v[j].w;
    }
    float ws = waveSum(s);
    if ((tid & 63) == 0) red[4 + (tid >> 6)] = ws;
    __syncthreads();
    float tot = red[4] + red[5] + red[6] + red[7];
    float sc = (float)N_SP / tot;
#pragma unroll
    for (int j = 0; j < 4; j++) {
        v[j].x *= sc; v[j].y *= sc; v[j].z *= sc; v[j].w *= sc;
        ((float4*)row)[j * 256 + tid] = v[j];
    }
}

// ---------------------------------------------------------------------------
// kv[bh,d,e] = (1/N) sum_t rope(k'*p)[t,d] * v[t,e]     (k' already elu1'd)
// kmean[bh,d] = (1/N) sum_t (k'*p)[t,d]
// ---------------------------------------------------------------------------
__global__ __launch_bounds__(256) void kv_kernel(
    const float* __restrict__ QKV, const float* __restrict__ eff,
    const float* __restrict__ sinp, const float* __restrict__ cosp,
    float* __restrict__ kv, float* __restrict__ kmean)
{
    int sp = blockIdx.x;
    int h = blockIdx.y, b = blockIdx.z;
    int bh = b * 8 + h;
    int tid = threadIdx.x;
    int r = tid >> 2, quad = tid & 3;
    const float* krow = QKV + ((size_t)b * CH_STRIDE + 512 + h * 64 + r) * N_SP;
    const float* vrow = QKV + ((size_t)b * CH_STRIDE + 1024 + h * 64 + r) * N_SP;
    const float* prow = eff + (size_t)bh * N_SP;
    __shared__ float ksr[64 * 65];
    __shared__ float vs[64 * 65];
    int dg = tid >> 4, eg = tid & 15;
    float acc[4][4];
#pragma unroll
    for (int i = 0; i < 4; i++)
#pragma unroll
        for (int j = 0; j < 4; j++) acc[i][j] = 0.f;
    float km = 0.f;
    float sgn = (r & 1) ? 1.f : -1.f;

    for (int c = 0; c < 8; c++) {
        int t0 = sp * 512 + c * 64;
        int tb = t0 + quad * 16;
        float kx[16], vv[16];
#pragma unroll
        for (int i4 = 0; i4 < 4; i4++) {
            float4 kf = *(const float4*)(krow + tb + i4 * 4);
            float4 pf = *(const float4*)(prow + tb + i4 * 4);
            float4 vf = *(const float4*)(vrow + tb + i4 * 4);
            kx[i4 * 4 + 0] = kf.x * pf.x;
            kx[i4 * 4 + 1] = kf.y * pf.y;
            kx[i4 * 4 + 2] = kf.z * pf.z;
            kx[i4 * 4 + 3] = kf.w * pf.w;
            vv[i4 * 4 + 0] = vf.x; vv[i4 * 4 + 1] = vf.y;
            vv[i4 * 4 + 2] = vf.z; vv[i4 * 4 + 3] = vf.w;
        }
#pragma unroll
        for (int i = 0; i < 16; i++) km += kx[i];
        __syncthreads();
#pragma unroll
        for (int i = 0; i < 16; i++) {
            float partner = __shfl_xor(kx[i], 4);
            int t = tb + i;
            float sv = sinp[(size_t)t * 64 + r];
            float cv = cosp[(size_t)t * 64 + r];
            float kr = kx[i] * cv + sgn * partner * sv;
            ksr[r * 65 + (t - t0)] = kr;
            vs[r * 65 + (t - t0)] = vv[i];
        }
        __syncthreads();
#pragma unroll 8
        for (int t = 0; t < 64; t++) {
            float a[4], bb[4];
#pragma unroll
            for (int i = 0; i < 4; i++) a[i] = ksr[(dg * 4 + i) * 65 + t];
#pragma unroll
            for (int j = 0; j < 4; j++) bb[j] = vs[(eg * 4 + j) * 65 + t];
#pragma unroll
            for (int i = 0; i < 4; i++)
#pragma unroll
                for (int j = 0; j < 4; j++) acc[i][j] += a[i] * bb[j];
        }
    }
#pragma unroll
    for (int i = 0; i < 4; i++)
#pragma unroll
        for (int j = 0; j < 4; j++)
            atomicAdd(&kv[((size_t)bh * 64 + dg * 4 + i) * 64 + eg * 4 + j],
                      acc[i][j] * (1.f / N_SP));
    km += __shfl_xor(km, 1);
    km += __shfl_xor(km, 2);
    if (quad == 0) atomicAdd(&kmean[(size_t)bh * 64 + r], km * (1.f / N_SP));
}

// ---------------------------------------------------------------------------
// res[b, 512 + h*64+e, t] = z[t] * sum_d qrope[t,d]*kv[d,e]   (q' already elu1'd)
// ---------------------------------------------------------------------------
__global__ __launch_bounds__(256) void res_kernel(
    const float* __restrict__ QKV, const float* __restrict__ kv,
    const float* __restrict__ kmean,
    const float* __restrict__ sinp, const float* __restrict__ cosp,
    float* __restrict__ res)
{
    int tc = blockIdx.x;
    int h = blockIdx.y, b = blockIdx.z;
    int bh = b * 8 + h;
    int tid = threadIdx.x;
    int t0 = tc * 64;
    __shared__ float qsr[64 * 65];
    __shared__ float qse[64 * 65];
    __shared__ float kvs[64 * 65];
    __shared__ float zs[64];
    __shared__ float kms[64];
#pragma unroll
    for (int j = 0; j < 16; j++) {
        int lin = j * 256 + tid;
        kvs[(lin >> 6) * 65 + (lin & 63)] = kv[(size_t)bh * 4096 + lin];
    }
    if (tid < 64) kms[tid] = kmean[(size_t)bh * 64 + tid];

    int r = tid >> 2, quad = tid & 3;
    const float* qrow = QKV + ((size_t)b * CH_STRIDE + h * 64 + r) * N_SP;
    float sgn = (r & 1) ? 1.f : -1.f;
    int tb = t0 + quad * 16;
#pragma unroll
    for (int i4 = 0; i4 < 4; i4++) {
        float4 qf = *(const float4*)(qrow + tb + i4 * 4);
        float qe[4] = { qf.x, qf.y, qf.z, qf.w };
#pragma unroll
        for (int ii = 0; ii < 4; ii++) {
            float partner = __shfl_xor(qe[ii], 4);
            int t = tb + i4 * 4 + ii;
            float sv = sinp[(size_t)t * 64 + r];
            float cv = cosp[(size_t)t * 64 + r];
            qse[r * 65 + (t - t0)] = qe[ii];
            qsr[r * 65 + (t - t0)] = qe[ii] * cv + sgn * partner * sv;
        }
    }
    __syncthreads();
    if (tid < 64) {
        float s = 0.f;
#pragma unroll 8
        for (int d = 0; d < 64; d++) s += qse[d * 65 + tid] * kms[d];
        zs[tid] = 1.f / (s + 1e-6f);
    }
    __syncthreads();

    int eg = tid >> 4, tg = tid & 15;
    float acc[4][4];
#pragma unroll
    for (int j = 0; j < 4; j++)
#pragma unroll
        for (int i = 0; i < 4; i++) acc[j][i] = 0.f;
#pragma unroll 4
    for (int d = 0; d < 64; d++) {
        float qv[4], kvv[4];
#pragma unroll
        for (int i = 0; i < 4; i++) qv[i] = qsr[d * 65 + tg * 4 + i];
#pragma unroll
        for (int j = 0; j < 4; j++) kvv[j] = kvs[d * 65 + eg * 4 + j];
#pragma unroll
        for (int j = 0; j < 4; j++)
#pragma unroll
            for (int i = 0; i < 4; i++) acc[j][i] += kvv[j] * qv[i];
    }
    float* rb = res + ((size_t)b * CH_STRIDE + 512 + h * 64) * N_SP;
#pragma unroll
    for (int j = 0; j < 4; j++) {
        float4 o4;
        o4.x = acc[j][0] * zs[tg * 4 + 0];
        o4.y = acc[j][1] * zs[tg * 4 + 1];
        o4.z = acc[j][2] * zs[tg * 4 + 2];
        o4.w = acc[j][3] * zs[tg * 4 + 3];
        *(float4*)(rb + (size_t)(eg * 4 + j) * N_SP + t0 + tg * 4) = o4;
    }
}

// ---------------------------------------------------------------------------
// lepe: res[b, 512+c, n] += b_lepe[c] + depthwise 5x5 conv of v channel c.
// ---------------------------------------------------------------------------
#define LPS 73   // padded LDS row stride (floats)
__global__ __launch_bounds__(256) void lepe_kernel(
    const float* __restrict__ QKV, const float* __restrict__ wl,
    const float* __restrict__ bl, float* __restrict__ res)
{
    int c = blockIdx.x & 511;
    int b = blockIdx.x >> 9;
    __shared__ float img[68 * LPS];
    int tid = threadIdx.x;
    const float* vb = QKV + ((size_t)b * CH_STRIDE + 1024 + c) * N_SP;

    for (int i = tid; i < 68 * LPS; i += 256) img[i] = 0.f;
    __syncthreads();
#pragma unroll
    for (int i = 0; i < 4; i++) {
        int p = i * 256 + tid;          // float4 index
        float4 v4 = ((const float4*)vb)[p];
        int y = p >> 4;
        int x = (p & 15) * 4;
        float* dst = &img[(y + 2) * LPS + (x + 2)];
        dst[0] = v4.x; dst[1] = v4.y; dst[2] = v4.z; dst[3] = v4.w;
    }
    float w[25];
    const float* wc = wl + c * 25;
#pragma unroll
    for (int i = 0; i < 25; i++) w[i] = wc[i];
    float bias = bl[c];
    __syncthreads();

    int y  = tid >> 2;
    int x0 = (tid & 3) * 16;
    float acc[16];
#pragma unroll
    for (int u = 0; u < 16; u++) acc[u] = bias;
#pragma unroll
    for (int i = 0; i < 5; i++) {
        float rowv[20];
#pragma unroll
        for (int q = 0; q < 20; q++)
            rowv[q] = img[(y + i) * LPS + x0 + q];
#pragma unroll
        for (int j = 0; j < 5; j++)
#pragma unroll
            for (int u = 0; u < 16; u++)
                acc[u] += rowv[u + j] * w[i * 5 + j];
    }
    float* rr = res + ((size_t)b * CH_STRIDE + 512 + c) * N_SP + y * 64 + x0;
#pragma unroll
    for (int q = 0; q < 4; q++) {
        float4 r4 = *(const float4*)&rr[q * 4];
        r4.x += acc[q * 4 + 0]; r4.y += acc[q * 4 + 1];
        r4.z += acc[q * 4 + 2]; r4.w += acc[q * 4 + 3];
        *(float4*)&rr[q * 4] = r4;
    }
}

// ---------------------------------------------------------------------------
extern "C" void kernel_launch(void* const* d_in, const int* in_sizes, int n_in,
                              void* d_out, int out_size, void* d_ws, size_t ws_size,
                              hipStream_t stream)
{
    const float* x      = (const float*)d_in[0];
    const float* sinp   = (const float*)d_in[1];
    const float* cosp   = (const float*)d_in[2];
    const float* w_qkvo = (const float*)d_in[3];
    const float* b_qkvo = (const float*)d_in[4];
    const float* w_lepe = (const float*)d_in[5];
    const float* b_lepe = (const float*)d_in[6];
    const float* w_proj = (const float*)d_in[7];
    const float* b_proj = (const float*)d_in[8];
    float* out = (float*)d_out;
    float* ws  = (float*)d_ws;

    // workspace layout (float offsets) — unchanged ~203.5 MB layout:
    float* qkv   = ws;                        // 8*1536*4096 = 50331648
    float* eff   = ws + 50331648;             // 64*4096     = 262144
    float* qmean = ws + 50593792;             // 64*64       = 4096  (raw sums now)
    float* kmean = ws + 50597888;             // 64*64       = 4096
    float* kv    = ws + 50601984;             // 64*64*64    = 262144

    // scratch overlays (no workspace growth):
    unsigned short* xT    = (unsigned short*)out;                     // 8*4096*512
    unsigned short* wq_bf = (unsigned short*)out + 16777216;          // 2048*512
    unsigned short* wp_bf = (unsigned short*)kv;                      // 512*512
    unsigned short* gT    = (unsigned short*)(qkv + (size_t)1024 * N_SP);

    // zero qsum + kmean + kv (contiguous)
    hipMemsetAsync(qmean, 0, (4096 + 4096 + 262144) * sizeof(float), stream);

    convert_bf16<<<1024, 256, 0, stream>>>(w_qkvo, wq_bf, 262144);
    transpose_x<<<dim3(64, 8, 8), 256, 0, stream>>>(x, xT);

    // QKV GEMM: stores elu1(q), elu1(k), raw v; accumulates qsum atomics
    gemm_bf16_fast<true><<<dim3(32, 12, 8), 256, 0, stream>>>(
        wq_bf, b_qkvo, xT, (size_t)N_SP * DIMC, qkv, CH_STRIDE, qmean);

    logits_kernel<<<dim3(16, 8, 8), 256, 0, stream>>>(qkv, qmean, eff);
    softmax_kernel<<<64, 256, 0, stream>>>(eff);
    kv_kernel<<<dim3(8, 8, 8), 256, 0, stream>>>(qkv, eff, sinp, cosp, kv, kmean);
    res_kernel<<<dim3(64, 8, 8), 256, 0, stream>>>(qkv, kv, kmean, sinp, cosp, qkv);

    convert_bf16<<<256, 256, 0, stream>>>(w_proj, wp_bf, 65536);  // kv region dead now
    lepe_kernel<<<4096, 256, 0, stream>>>(qkv, w_lepe, b_lepe, qkv);

    // o = W_o x  -> overwrite dead q region (ch 0..511)
    gemm_bf16_fast<false><<<dim3(32, 4, 8), 256, 0, stream>>>(
        wq_bf + (size_t)1536 * DIMC, b_qkvo + 1536, xT, (size_t)N_SP * DIMC,
        qkv, CH_STRIDE, nullptr);

    // gT = bf16((res+lepe) * o), transposed into dead v region
    gate_transpose<<<dim3(64, 8, 8), 256, 0, stream>>>(qkv);

    // out = W_proj gT + b_proj
    gemm_bf16_fast<false><<<dim3(32, 4, 8), 256, 0, stream>>>(
        wp_bf, b_proj, gT, (size_t)CH_STRIDE * N_SP * 2, out, DIMC, nullptr);
}